// Round 1
// baseline (350.826 us; speedup 1.0000x reference)
//
#include <hip/hip_runtime.h>

#define C 192
#define H 56
#define W 56
#define HW (H * W)
#define CHW (C * H * W)
#define BLOCK 256

__global__ __launch_bounds__(BLOCK) void msgdc_kernel(
    const float* __restrict__ x,
    const float* __restrict__ bias,
    const float* __restrict__ conv_w,
    const float* __restrict__ conv_b,
    const float* __restrict__ move1,
    const float* __restrict__ alpha,
    const float* __restrict__ move2,
    const float* __restrict__ ln_gamma,
    const float* __restrict__ ln_beta,
    float* __restrict__ out)
{
    // per-channel params staged once per block
    __shared__ float wts[C][27];   // 9 weights x 3 dilations
    __shared__ float kc[3][C];     // conv_b - move1 + bias*sum(w)  (bias fold)
    __shared__ float al[3][C];     // PReLU alpha
    __shared__ float m2s[C];       // sum_i move2[i][c]
    __shared__ float gam[C], bet[C];
    __shared__ float tile[C * W];  // pre-LN row, 43 KB
    __shared__ float ps[4][W], pq[4][W];
    __shared__ float mean_s[W], rstd_s[W];

    const int t = threadIdx.x;
    const int blk = blockIdx.x;   // b*H + h
    const int b = blk / H;
    const int h = blk - b * H;

    if (t < C) {
        const int c = t;
        const float bs = bias[c];
        float m2sum = 0.f;
        #pragma unroll
        for (int i = 0; i < 3; ++i) {
            float sw = 0.f;
            #pragma unroll
            for (int j = 0; j < 9; ++j) {
                float wv = conv_w[(i * C + c) * 9 + j];
                wts[c][i * 9 + j] = wv;
                sw += wv;
            }
            kc[i][c] = conv_b[i * C + c] - move1[i * C + c] + bs * sw;
            al[i][c] = alpha[i * C + c];
            m2sum += move2[i * C + c];
        }
        m2s[c] = m2sum;
        gam[c] = ln_gamma[c];
        bet[c] = ln_beta[c];
    }
    __syncthreads();

    // ---- conv + RPReLU accumulate over 3 dilations ----
    const float* xb_base = x + (size_t)b * CHW;
    for (int idx = t; idx < C * W; idx += BLOCK) {
        const int c = idx / W;
        const int w = idx - c * W;
        const float* xc = xb_base + c * HW;
        float acc = m2s[c];
        #pragma unroll
        for (int i = 0; i < 3; ++i) {
            const int d = (i == 0) ? 1 : (i == 1) ? 3 : 5;
            float y = kc[i][c];
            #pragma unroll
            for (int kh = 0; kh < 3; ++kh) {
                const int r = h + (kh - 1) * d;
                const bool rv = (unsigned)r < (unsigned)H;
                const float* xr = xc + r * W;
                #pragma unroll
                for (int kw = 0; kw < 3; ++kw) {
                    const int cw = w + (kw - 1) * d;
                    const bool cv = (unsigned)cw < (unsigned)W;
                    const float v = (rv && cv) ? xr[cw] : 0.f;
                    y = fmaf(v, wts[c][i * 9 + kh * 3 + kw], y);
                }
            }
            // RPReLU (move1 already folded into kc): z>=0 ? z : a*z
            acc += fmaxf(y, 0.f) + al[i][c] * fminf(y, 0.f);
        }
        tile[idx] = acc;
    }
    __syncthreads();

    // ---- LayerNorm over channels, per pixel w ----
    if (t < 4 * W) {
        const int w = t % W;
        const int g = t / W;
        float s = 0.f, q = 0.f;
        for (int c = g; c < C; c += 4) {
            const float v = tile[c * W + w];
            s += v;
            q += v * v;
        }
        ps[g][w] = s;
        pq[g][w] = q;
    }
    __syncthreads();
    if (t < W) {
        const float s = ps[0][t] + ps[1][t] + ps[2][t] + ps[3][t];
        const float q = pq[0][t] + pq[1][t] + pq[2][t] + pq[3][t];
        const float m = s * (1.f / C);
        const float var = q * (1.f / C) - m * m;
        mean_s[t] = m;
        rstd_s[t] = rsqrtf(var + 1e-5f);
    }
    __syncthreads();

    float* op = out + (size_t)b * CHW + h * W;
    for (int idx = t; idx < C * W; idx += BLOCK) {
        const int c = idx / W;
        const int w = idx - c * W;
        const float v = (tile[idx] - mean_s[w]) * rstd_s[w];
        op[c * HW + w] = fmaf(v, gam[c], bet[c]);
    }
}

extern "C" void kernel_launch(void* const* d_in, const int* in_sizes, int n_in,
                              void* d_out, int out_size, void* d_ws, size_t ws_size,
                              hipStream_t stream) {
    const float* x       = (const float*)d_in[0];
    const float* bias    = (const float*)d_in[1];
    const float* conv_w  = (const float*)d_in[2];
    const float* conv_b  = (const float*)d_in[3];
    const float* move1   = (const float*)d_in[4];
    const float* alpha   = (const float*)d_in[5];
    const float* move2   = (const float*)d_in[6];
    const float* ln_g    = (const float*)d_in[7];
    const float* ln_b    = (const float*)d_in[8];
    float* out = (float*)d_out;

    const int B = 32;
    dim3 grid(B * H);
    dim3 block(BLOCK);
    msgdc_kernel<<<grid, block, 0, stream>>>(x, bias, conv_w, conv_b,
                                             move1, alpha, move2, ln_g, ln_b, out);
}

// Round 2
// 350.555 us; speedup vs baseline: 1.0008x; 1.0008x over previous
//
#include <hip/hip_runtime.h>

#define C 192
#define H 56
#define W 56
#define HW (H * W)
#define CHW (C * HW)
#define NB 32
#define BLOCK 256

// bf16 helpers (round-half-up is plenty for 0.169 absmax budget)
__device__ __forceinline__ unsigned short f2bf(float v) {
    return (unsigned short)((__float_as_uint(v) + 0x8000u) >> 16);
}
__device__ __forceinline__ float bf2f(unsigned short u) {
    return __uint_as_float(((unsigned int)u) << 16);
}

__global__ __launch_bounds__(BLOCK, 4) void msgdc_kernel(
    const float* __restrict__ x,
    const float* __restrict__ bias,
    const float* __restrict__ conv_w,
    const float* __restrict__ conv_b,
    const float* __restrict__ move1,
    const float* __restrict__ alpha,
    const float* __restrict__ move2,
    const float* __restrict__ ln_gamma,
    const float* __restrict__ ln_beta,
    float* __restrict__ out)
{
    __shared__ unsigned short tile[C * 64];  // bf16 pre-LN values, padded to 64 wide
    __shared__ float ps[4][64];
    __shared__ float pq[4][64];

    const int t = threadIdx.x;
    const int lane = t & 63;
    // wave id forced uniform so per-channel param loads scalarize to s_load
    const int wv = __builtin_amdgcn_readfirstlane(t >> 6);

    // XCD-aware swizzle: each XCD gets a contiguous run of (b,h) so h-halo
    // rows are reused inside that XCD's L2.
    const int blk = blockIdx.x;
    const int gid = (blk & 7) * 224 + (blk >> 3);
    const int b = gid / H;
    const int h = gid - b * H;

    // hoisted shuffle source-lane registers (bpermute wraps mod 64; lanes
    // 56..63 carry zeros so both w-edges fall out for free)
    const int i_m1 = (lane - 1) & 63, i_p1 = (lane + 1) & 63;
    const int i_m3 = (lane - 3) & 63, i_p3 = (lane + 3) & 63;
    const int i_m5 = (lane - 5) & 63, i_p5 = (lane + 5) & 63;

    const bool lv = lane < W;
    // uniform row-validity predicates
    const bool hm5 = (h >= 5), hm3 = (h >= 3), hm1 = (h >= 1);
    const bool hp1 = (h <= H - 2), hp3 = (h <= H - 4), hp5 = (h <= H - 6);

    const float* xb = x + (size_t)b * CHW + h * W + lane;

    float s_acc = 0.f, q_acc = 0.f;

    for (int j = 0; j < 48; ++j) {
        const int c = wv * 48 + j;  // uniform per wave

        // ---- uniform (scalar) parameter loads ----
        const float bs = bias[c];
        float wt[27];
        #pragma unroll
        for (int i = 0; i < 3; ++i)
            #pragma unroll
            for (int k = 0; k < 9; ++k)
                wt[i * 9 + k] = conv_w[(size_t)(i * C + c) * 9 + k];
        const float kc0 = conv_b[0 * C + c] - move1[0 * C + c];
        const float kc1 = conv_b[1 * C + c] - move1[1 * C + c];
        const float kc2 = conv_b[2 * C + c] - move1[2 * C + c];
        const float a0 = alpha[0 * C + c];
        const float a1 = alpha[1 * C + c];
        const float a2 = alpha[2 * C + c];
        const float m2 = move2[0 * C + c] + move2[1 * C + c] + move2[2 * C + c];

        // ---- 7 coalesced row loads (x + bias, zero outside) ----
        const float* xc = xb + (size_t)c * HW;
        float r0 = (hm5 && lv) ? xc[-5 * W] + bs : 0.f;  // h-5
        float r1 = (hm3 && lv) ? xc[-3 * W] + bs : 0.f;  // h-3
        float r2 = (hm1 && lv) ? xc[-1 * W] + bs : 0.f;  // h-1
        float r3 = (lv)        ? xc[0]      + bs : 0.f;  // h
        float r4 = (hp1 && lv) ? xc[1 * W]  + bs : 0.f;  // h+1
        float r5 = (hp3 && lv) ? xc[3 * W]  + bs : 0.f;  // h+3
        float r6 = (hp5 && lv) ? xc[5 * W]  + bs : 0.f;  // h+5

        float acc = m2;
        // ---- dilation 1: rows r2,r3,r4, wt[0..8] ----
        {
            float y = kc0;
            y = fmaf(__shfl(r2, i_m1), wt[0], y);
            y = fmaf(r2,               wt[1], y);
            y = fmaf(__shfl(r2, i_p1), wt[2], y);
            y = fmaf(__shfl(r3, i_m1), wt[3], y);
            y = fmaf(r3,               wt[4], y);
            y = fmaf(__shfl(r3, i_p1), wt[5], y);
            y = fmaf(__shfl(r4, i_m1), wt[6], y);
            y = fmaf(r4,               wt[7], y);
            y = fmaf(__shfl(r4, i_p1), wt[8], y);
            acc += fmaxf(y, 0.f) + a0 * fminf(y, 0.f);
        }
        // ---- dilation 3: rows r1,r3,r5, wt[9..17] ----
        {
            float y = kc1;
            y = fmaf(__shfl(r1, i_m3), wt[9],  y);
            y = fmaf(r1,               wt[10], y);
            y = fmaf(__shfl(r1, i_p3), wt[11], y);
            y = fmaf(__shfl(r3, i_m3), wt[12], y);
            y = fmaf(r3,               wt[13], y);
            y = fmaf(__shfl(r3, i_p3), wt[14], y);
            y = fmaf(__shfl(r5, i_m3), wt[15], y);
            y = fmaf(r5,               wt[16], y);
            y = fmaf(__shfl(r5, i_p3), wt[17], y);
            acc += fmaxf(y, 0.f) + a1 * fminf(y, 0.f);
        }
        // ---- dilation 5: rows r0,r3,r6, wt[18..26] ----
        {
            float y = kc2;
            y = fmaf(__shfl(r0, i_m5), wt[18], y);
            y = fmaf(r0,               wt[19], y);
            y = fmaf(__shfl(r0, i_p5), wt[20], y);
            y = fmaf(__shfl(r3, i_m5), wt[21], y);
            y = fmaf(r3,               wt[22], y);
            y = fmaf(__shfl(r3, i_p5), wt[23], y);
            y = fmaf(__shfl(r6, i_m5), wt[24], y);
            y = fmaf(r6,               wt[25], y);
            y = fmaf(__shfl(r6, i_p5), wt[26], y);
            acc += fmaxf(y, 0.f) + a2 * fminf(y, 0.f);
        }

        s_acc += acc;
        q_acc += acc * acc;
        tile[c * 64 + lane] = f2bf(acc);
    }

    ps[wv][lane] = s_acc;
    pq[wv][lane] = q_acc;
    __syncthreads();

    const float s = ps[0][lane] + ps[1][lane] + ps[2][lane] + ps[3][lane];
    const float q = pq[0][lane] + pq[1][lane] + pq[2][lane] + pq[3][lane];
    const float m = s * (1.f / C);
    const float rstd = rsqrtf(q * (1.f / C) - m * m + 1e-5f);

    if (lv) {
        float* ob = out + (size_t)b * CHW + h * W + lane;
        for (int j = 0; j < 48; ++j) {
            const int c = wv * 48 + j;
            const float g  = ln_gamma[c];
            const float be = ln_beta[c];
            const float v = bf2f(tile[c * 64 + lane]);
            ob[(size_t)c * HW] = fmaf((v - m) * rstd, g, be);
        }
    }
}

extern "C" void kernel_launch(void* const* d_in, const int* in_sizes, int n_in,
                              void* d_out, int out_size, void* d_ws, size_t ws_size,
                              hipStream_t stream) {
    const float* x       = (const float*)d_in[0];
    const float* bias    = (const float*)d_in[1];
    const float* conv_w  = (const float*)d_in[2];
    const float* conv_b  = (const float*)d_in[3];
    const float* move1   = (const float*)d_in[4];
    const float* alpha   = (const float*)d_in[5];
    const float* move2   = (const float*)d_in[6];
    const float* ln_g    = (const float*)d_in[7];
    const float* ln_b    = (const float*)d_in[8];
    float* out = (float*)d_out;

    dim3 grid(NB * H);
    dim3 block(BLOCK);
    msgdc_kernel<<<grid, block, 0, stream>>>(x, bias, conv_w, conv_b,
                                             move1, alpha, move2, ln_g, ln_b, out);
}

// Round 3
// 202.832 us; speedup vs baseline: 1.7296x; 1.7283x over previous
//
#include <hip/hip_runtime.h>

#define C 192
#define H 56
#define W 56
#define HW (H * W)
#define CHW (C * HW)
#define NB 32
#define PPS 36
#define EPSLN 1e-5f

// ---- DPP cross-lane helpers (16-lane rows == our sub-groups) ----
// row_shl:N => dst[n] = src[n+N] (fetch from higher lane), vacated -> 0
// row_shr:N => dst[n] = src[n-N] (fetch from lower lane),  vacated -> 0
#define CTL_SHL1 0x101
#define CTL_SHL2 0x102
#define CTL_SHR1 0x111
#define CTL_SHR2 0x112

template<int CTRL>
__device__ __forceinline__ float dppf(float v) {
    return __int_as_float(__builtin_amdgcn_update_dpp(
        0, __float_as_int(v), CTRL, 0xf, 0xf, true));
}

struct __attribute__((aligned(16))) f4 { float x, y, z, w; };

__device__ __forceinline__ f4 f4z() { return {0.f, 0.f, 0.f, 0.f}; }
__device__ __forceinline__ f4 f4b(float s) { return {s, s, s, s}; }
__device__ __forceinline__ f4 fma4(f4 a, float s, f4 c) {
    return { fmaf(a.x, s, c.x), fmaf(a.y, s, c.y),
             fmaf(a.z, s, c.z), fmaf(a.w, s, c.w) };
}
// lane l holds w in [4l, 4l+4); shifted view: comp k = row[4l+k+s]
__device__ __forceinline__ f4 shp1(f4 v){ return { v.y, v.z, v.w, dppf<CTL_SHL1>(v.x) }; }
__device__ __forceinline__ f4 shm1(f4 v){ return { dppf<CTL_SHR1>(v.w), v.x, v.y, v.z }; }
__device__ __forceinline__ f4 shp3(f4 v){ return { v.w, dppf<CTL_SHL1>(v.x),
                                                   dppf<CTL_SHL1>(v.y), dppf<CTL_SHL1>(v.z) }; }
__device__ __forceinline__ f4 shm3(f4 v){ return { dppf<CTL_SHR1>(v.y), dppf<CTL_SHR1>(v.z),
                                                   dppf<CTL_SHR1>(v.w), v.x }; }
__device__ __forceinline__ f4 shp5(f4 v){ return { dppf<CTL_SHL1>(v.y), dppf<CTL_SHL1>(v.z),
                                                   dppf<CTL_SHL1>(v.w), dppf<CTL_SHL2>(v.x) }; }
__device__ __forceinline__ f4 shm5(f4 v){ return { dppf<CTL_SHR2>(v.w), dppf<CTL_SHR1>(v.x),
                                                   dppf<CTL_SHR1>(v.y), dppf<CTL_SHR1>(v.z) }; }

__device__ __forceinline__ f4 prelu_acc(f4 acc, f4 y, float a) {
    acc.x += fmaxf(y.x, 0.f) + a * fminf(y.x, 0.f);
    acc.y += fmaxf(y.y, 0.f) + a * fminf(y.y, 0.f);
    acc.z += fmaxf(y.z, 0.f) + a * fminf(y.z, 0.f);
    acc.w += fmaxf(y.w, 0.f) + a * fminf(y.w, 0.f);
    return acc;
}

// ---- prep: fold params into packed 36-float records (d_ws) ----
__global__ void prep_kernel(const float* __restrict__ bias,
                            const float* __restrict__ conv_w,
                            const float* __restrict__ conv_b,
                            const float* __restrict__ move1,
                            const float* __restrict__ alpha,
                            const float* __restrict__ move2,
                            const float* __restrict__ ln_g,
                            const float* __restrict__ ln_b,
                            float* __restrict__ pp, float* __restrict__ gb) {
    const int c = threadIdx.x;
    if (c >= C) return;
    float* pc = pp + c * PPS;
    #pragma unroll
    for (int i = 0; i < 3; ++i)
        #pragma unroll
        for (int k = 0; k < 9; ++k)
            pc[i * 9 + k] = conv_w[(size_t)(i * C + c) * 9 + k];
    #pragma unroll
    for (int i = 0; i < 3; ++i) {
        pc[27 + i] = conv_b[i * C + c] - move1[i * C + c];
        pc[30 + i] = alpha[i * C + c];
    }
    pc[33] = bias[c];
    pc[34] = move2[0 * C + c] + move2[1 * C + c] + move2[2 * C + c];
    pc[35] = 0.f;
    gb[2 * c]     = ln_g[c];
    gb[2 * c + 1] = ln_b[c];
}

__global__ __launch_bounds__(256, 3) void msgdc_kernel(
    const float* __restrict__ x, const float* __restrict__ pp,
    const float* __restrict__ gb, float* __restrict__ out)
{
    __shared__ float tile[C * W];        // 43 KB fp32 pre-LN (own-lane only)
    __shared__ float sred[4][16][8];     // cross-wave LN partials

    const int t = threadIdx.x;
    const int lane = t & 63;
    const int wv = __builtin_amdgcn_readfirstlane(t >> 6);
    const int l = lane & 15;             // position within 16-lane sub-group
    const bool act = (l < 14);           // 14 lanes x float4 = 56 pixels
    const float act_f = act ? 1.f : 0.f;
    const int lw = act ? 4 * l : 52;     // clamped (safe) w offset for idle lanes

    const int blk = blockIdx.x;
    const int gid = (blk & 7) * 224 + (blk >> 3);   // XCD-contiguous (b,h)
    const int b = gid / H;
    const int h = gid - b * H;

    // uniform row validity, offsets {-5,-3,-1,0,+1,+3,+5}
    const bool vr[7] = { h >= 5, h >= 3, h >= 1, true,
                         h <= H - 2, h <= H - 4, h <= H - 6 };
    const int  ro[7] = { -5 * W, -3 * W, -1 * W, 0, 1 * W, 3 * W, 5 * W };
    float vm[7];
    #pragma unroll
    for (int k = 0; k < 7; ++k) vm[k] = vr[k] ? 1.f : 0.f;

    const int cbase = wv * 48 + (lane >> 4);        // channel for j=0
    const float* xc = x + (size_t)b * CHW + (size_t)cbase * HW + h * W + lw;

    f4 cur[7], nxt[7];
    #pragma unroll
    for (int k = 0; k < 7; ++k)
        nxt[k] = vr[k] ? *(const f4*)(xc + ro[k]) : f4z();

    f4 s4 = f4z(), q4 = f4z();

    #pragma unroll 2
    for (int j = 0; j < 12; ++j) {
        const int c = cbase + 4 * j;
        #pragma unroll
        for (int k = 0; k < 7; ++k) cur[k] = nxt[k];

        // packed folded params (group-uniform address -> 4x16B/instr, L2-hot)
        const float* pc = pp + c * PPS;
        float wf[36];
        #pragma unroll
        for (int k = 0; k < 9; ++k)
            *(f4*)(wf + 4 * k) = *(const f4*)(pc + 4 * k);

        // prefetch next channel's rows while we compute
        if (j < 11) {
            const float* xn = xc + (size_t)(4 * (j + 1)) * HW;
            #pragma unroll
            for (int k = 0; k < 7; ++k)
                nxt[k] = vr[k] ? *(const f4*)(xn + ro[k]) : f4z();
        }

        const float bs = wf[33];
        // bias applied to valid in-image samples only; idle lanes forced to 0
        f4 r[7];
        #pragma unroll
        for (int k = 0; k < 7; ++k) {
            const float bk = bs * vm[k] * act_f;   // 0 for invalid rows / idle lanes
            r[k].x = fmaf(cur[k].x, act_f, bk);
            r[k].y = fmaf(cur[k].y, act_f, bk);
            r[k].z = fmaf(cur[k].z, act_f, bk);
            r[k].w = fmaf(cur[k].w, act_f, bk);
        }

        f4 acc = f4b(wf[34]);   // m2 fold
        {   // d = 1: rows r[2],r[3],r[4], weights wf[0..8]
            f4 y = f4b(wf[27]);
            y = fma4(shm1(r[2]), wf[0], y);
            y = fma4(r[2],       wf[1], y);
            y = fma4(shp1(r[2]), wf[2], y);
            y = fma4(shm1(r[3]), wf[3], y);
            y = fma4(r[3],       wf[4], y);
            y = fma4(shp1(r[3]), wf[5], y);
            y = fma4(shm1(r[4]), wf[6], y);
            y = fma4(r[4],       wf[7], y);
            y = fma4(shp1(r[4]), wf[8], y);
            acc = prelu_acc(acc, y, wf[30]);
        }
        {   // d = 3: rows r[1],r[3],r[5], weights wf[9..17]
            f4 y = f4b(wf[28]);
            y = fma4(shm3(r[1]), wf[9],  y);
            y = fma4(r[1],       wf[10], y);
            y = fma4(shp3(r[1]), wf[11], y);
            y = fma4(shm3(r[3]), wf[12], y);
            y = fma4(r[3],       wf[13], y);
            y = fma4(shp3(r[3]), wf[14], y);
            y = fma4(shm3(r[5]), wf[15], y);
            y = fma4(r[5],       wf[16], y);
            y = fma4(shp3(r[5]), wf[17], y);
            acc = prelu_acc(acc, y, wf[31]);
        }
        {   // d = 5: rows r[0],r[3],r[6], weights wf[18..26]
            f4 y = f4b(wf[29]);
            y = fma4(shm5(r[0]), wf[18], y);
            y = fma4(r[0],       wf[19], y);
            y = fma4(shp5(r[0]), wf[20], y);
            y = fma4(shm5(r[3]), wf[21], y);
            y = fma4(r[3],       wf[22], y);
            y = fma4(shp5(r[3]), wf[23], y);
            y = fma4(shm5(r[6]), wf[24], y);
            y = fma4(r[6],       wf[25], y);
            y = fma4(shp5(r[6]), wf[26], y);
            acc = prelu_acc(acc, y, wf[32]);
        }

        s4.x += acc.x; s4.y += acc.y; s4.z += acc.z; s4.w += acc.w;
        q4.x = fmaf(acc.x, acc.x, q4.x); q4.y = fmaf(acc.y, acc.y, q4.y);
        q4.z = fmaf(acc.z, acc.z, q4.z); q4.w = fmaf(acc.w, acc.w, q4.w);

        if (act) *(f4*)(tile + c * W + lw) = acc;   // own-lane stash, no barrier needed
    }

    // ---- LN reduction: cross-group (xor16/32 keeps l fixed), then cross-wave ----
    #pragma unroll
    for (int m = 16; m <= 32; m <<= 1) {
        s4.x += __shfl_xor(s4.x, m, 64); s4.y += __shfl_xor(s4.y, m, 64);
        s4.z += __shfl_xor(s4.z, m, 64); s4.w += __shfl_xor(s4.w, m, 64);
        q4.x += __shfl_xor(q4.x, m, 64); q4.y += __shfl_xor(q4.y, m, 64);
        q4.z += __shfl_xor(q4.z, m, 64); q4.w += __shfl_xor(q4.w, m, 64);
    }
    if (lane < 14) {
        *(f4*)&sred[wv][lane][0] = s4;
        *(f4*)&sred[wv][lane][4] = q4;
    }
    __syncthreads();

    f4 S = f4z(), Q = f4z();
    #pragma unroll
    for (int w2 = 0; w2 < 4; ++w2) {
        const f4 a = *(const f4*)&sred[w2][l][0];
        const f4 bq = *(const f4*)&sred[w2][l][4];
        S.x += a.x; S.y += a.y; S.z += a.z; S.w += a.w;
        Q.x += bq.x; Q.y += bq.y; Q.z += bq.z; Q.w += bq.w;
    }
    const float inv = 1.f / (float)C;
    f4 mean = { S.x * inv, S.y * inv, S.z * inv, S.w * inv };
    f4 rstd = { rsqrtf(Q.x * inv - mean.x * mean.x + EPSLN),
                rsqrtf(Q.y * inv - mean.y * mean.y + EPSLN),
                rsqrtf(Q.z * inv - mean.z * mean.z + EPSLN),
                rsqrtf(Q.w * inv - mean.w * mean.w + EPSLN) };

    float* ob = out + (size_t)b * CHW + (size_t)cbase * HW + h * W + lw;
    #pragma unroll 2
    for (int j = 0; j < 12; ++j) {
        const int c = cbase + 4 * j;
        const float ga = gb[2 * c], be = gb[2 * c + 1];
        if (act) {
            const f4 v = *(const f4*)(tile + c * W + lw);
            f4 o;
            o.x = fmaf((v.x - mean.x) * rstd.x, ga, be);
            o.y = fmaf((v.y - mean.y) * rstd.y, ga, be);
            o.z = fmaf((v.z - mean.z) * rstd.z, ga, be);
            o.w = fmaf((v.w - mean.w) * rstd.w, ga, be);
            *(f4*)(ob + (size_t)(4 * j) * HW) = o;
        }
    }
}

extern "C" void kernel_launch(void* const* d_in, const int* in_sizes, int n_in,
                              void* d_out, int out_size, void* d_ws, size_t ws_size,
                              hipStream_t stream) {
    const float* x       = (const float*)d_in[0];
    const float* bias    = (const float*)d_in[1];
    const float* conv_w  = (const float*)d_in[2];
    const float* conv_b  = (const float*)d_in[3];
    const float* move1   = (const float*)d_in[4];
    const float* alpha   = (const float*)d_in[5];
    const float* move2   = (const float*)d_in[6];
    const float* ln_g    = (const float*)d_in[7];
    const float* ln_b    = (const float*)d_in[8];
    float* out = (float*)d_out;

    float* pp = (float*)d_ws;                 // 192*36 floats
    float* gbp = pp + C * PPS;                // 192*2 floats

    prep_kernel<<<1, 256, 0, stream>>>(bias, conv_w, conv_b, move1, alpha,
                                       move2, ln_g, ln_b, pp, gbp);
    msgdc_kernel<<<NB * H, 256, 0, stream>>>(x, pp, gbp, out);
}